// Round 14
// baseline (2789.226 us; speedup 1.0000x reference)
//
#include <hip/hip_runtime.h>
#include <math.h>

#define TOKENS 4096
#define BATCH 64

typedef __attribute__((ext_vector_type(8))) short bf16x8;
typedef __attribute__((ext_vector_type(4))) float f32x4;
union U4B { uint4 u; bf16x8 b; };
union U2x2B { uint2 u[2]; bf16x8 b; };

__device__ __forceinline__ float wsum(float v) {
#pragma unroll
  for (int m = 32; m >= 1; m >>= 1) v += __shfl_xor(v, m);
  return v;
}
__device__ __forceinline__ unsigned short f2bf(float f) {
  unsigned u = __float_as_uint(f);
  u += 0x7fffu + ((u >> 16) & 1u);
  return (unsigned short)(u >> 16);
}
__device__ __forceinline__ float bflo(unsigned p) { return __uint_as_float(p << 16); }
__device__ __forceinline__ float bfhi(unsigned p) { return __uint_as_float(p & 0xffff0000u); }
__device__ __forceinline__ float sigmf(float x) { return 1.f / (1.f + expf(-x)); }

// ================= K_PRE: LN->x  |  weight transposes ==========
__global__ __launch_bounds__(256) void k_pre(
    const float* __restrict__ in, const float* __restrict__ lin_g,
    const float* __restrict__ lin_b, unsigned* __restrict__ x,
    const float* __restrict__ Wq, const float* __restrict__ Wv,
    const float* __restrict__ Wih, const float* __restrict__ Whh,
    const float* __restrict__ W1, const float* __restrict__ W2,
    float* __restrict__ WqT, float* __restrict__ WvT, float* __restrict__ WihT,
    float* __restrict__ WhhT, float* __restrict__ W1T, float* __restrict__ W2T) {
  int bid = blockIdx.x, tid = threadIdx.x;
  if (bid < 65536) {
    int row = bid * 4 + (tid >> 6);
    int lane = tid & 63;
    const float* p = in + (size_t)row * 256 + lane * 4;
    float4 v = *(const float4*)p;
    float s  = wsum(v.x + v.y + v.z + v.w);
    float sq = wsum(v.x * v.x + v.y * v.y + v.z * v.z + v.w * v.w);
    float mu = s * (1.f / 256.f);
    float var = sq * (1.f / 256.f) - mu * mu;
    float rs = rsqrtf(var + 1e-5f);
    float4 gg = *(const float4*)(lin_g + lane * 4);
    float4 bb = *(const float4*)(lin_b + lane * 4);
    float y0 = (v.x - mu) * rs * gg.x + bb.x;
    float y1 = (v.y - mu) * rs * gg.y + bb.y;
    float y2 = (v.z - mu) * rs * gg.z + bb.z;
    float y3 = (v.w - mu) * rs * gg.w + bb.w;
    uint2 o;
    o.x = (unsigned)f2bf(y0) | ((unsigned)f2bf(y1) << 16);
    o.y = (unsigned)f2bf(y2) | ((unsigned)f2bf(y3) << 16);
    *(uint2*)(x + (size_t)row * 128 + lane * 2) = o;
    return;
  }
  {
    __shared__ float t[32][33];
    int t2 = bid - 65536;
    const float* S; float* D; int R; int tile;
    if (t2 < 64)       { S = Wq;  D = WqT;  R = 256; tile = t2; }
    else if (t2 < 128) { S = Wv;  D = WvT;  R = 256; tile = t2 - 64; }
    else if (t2 < 192) { S = W1;  D = W1T;  R = 256; tile = t2 - 128; }
    else if (t2 < 256) { S = W2;  D = W2T;  R = 256; tile = t2 - 192; }
    else if (t2 < 448) { S = Wih; D = WihT; R = 768; tile = t2 - 256; }
    else               { S = Whh; D = WhhT; R = 768; tile = t2 - 448; }
    int rt = R >> 5;
    int r0 = (tile % rt) * 32, c0 = (tile / rt) * 32;
    int ci = tid & 31, r8 = tid >> 5;
#pragma unroll
    for (int k = 0; k < 4; ++k) {
      int r = r8 + k * 8;
      t[r][ci] = S[(size_t)(r0 + r) * 256 + c0 + ci];
    }
    __syncthreads();
#pragma unroll
    for (int k = 0; k < 4; ++k) {
      int r = r8 + k * 8;
      D[(size_t)(c0 + r) * R + r0 + ci] = t[ci][r];
    }
  }
}

// ========== K_QW0: slot init + first-iteration qw (uses WqT) ==========
__global__ __launch_bounds__(256) void k_qw0(
    const float* __restrict__ smu, const float* __restrict__ slsig,
    const float* __restrict__ noise, const float* __restrict__ lsl_g,
    const float* __restrict__ lsl_b, const float* __restrict__ WqT,
    const float* __restrict__ Wk, float* __restrict__ slots,
    unsigned* __restrict__ qwb) {
  __shared__ float ln[256];
  __shared__ float q[256];
  __shared__ float red[8];
  int n = blockIdx.x, s = blockIdx.y, tid = threadIdx.x;
  int sd = s * 256 + tid;
  float v = smu[sd] + expf(slsig[sd]) * noise[(size_t)n * 2048 + sd];
  slots[(size_t)n * 2048 + sd] = v;
  float ps = wsum(v), pq = wsum(v * v);
  if ((tid & 63) == 0) { red[tid >> 6] = ps; red[4 + (tid >> 6)] = pq; }
  __syncthreads();
  float sum = red[0] + red[1] + red[2] + red[3];
  float sqq = red[4] + red[5] + red[6] + red[7];
  float mu = sum * (1.f / 256.f);
  float var = sqq * (1.f / 256.f) - mu * mu;
  float rs = rsqrtf(var + 1e-5f);
  ln[tid] = (v - mu) * rs * lsl_g[tid] + lsl_b[tid];
  __syncthreads();
  float a = 0.f;
  for (int d = 0; d < 256; ++d) a += ln[d] * WqT[d * 256 + tid];
  q[tid] = a;
  __syncthreads();
  float c = 0.f;
  for (int e = 0; e < 256; ++e) c += q[e] * Wk[(size_t)e * 256 + tid];
  c *= 0.0625f;
  __syncthreads();
  ln[tid] = c;
  __syncthreads();
  if (tid < 128)
    qwb[((size_t)n * 8 + s) * 128 + tid] =
        (unsigned)f2bf(ln[2 * tid]) | ((unsigned)f2bf(ln[2 * tid + 1]) << 16);
}

// ========== K_ATTUP: att chunk (512 thr) + last-block update fusion ==========
// grid (64 chunks, 64 n). Per block: stage chunk, QK^T MFMA, exp (no max),
// PV split over 2 thread-halves. Then per-(it,n) counter; last of 64 blocks
// acquires all partials and runs the full slot update (sg = 0 then 4).
__global__ __launch_bounds__(512) void k_attup(
    const unsigned* __restrict__ x, unsigned* __restrict__ qwb,
    float* __restrict__ stats, float* __restrict__ axp,
    unsigned* __restrict__ cnt, int it, int doQw,
    const float* __restrict__ WvT, const float* __restrict__ WihT,
    const float* __restrict__ WhhT, const float* __restrict__ b_ih,
    const float* __restrict__ b_hh, const float* __restrict__ W1T,
    const float* __restrict__ b1, const float* __restrict__ W2T,
    const float* __restrict__ b2, const float* __restrict__ lml_g,
    const float* __restrict__ lml_b, const float* __restrict__ lsl_g,
    const float* __restrict__ lsl_b, const float* __restrict__ WqT,
    const float* __restrict__ Wk, float* __restrict__ slots) {
  __shared__ float poolf[12320];
  unsigned* xs = (unsigned*)poolf;   // [64][130]
  float* lsT = poolf + 8320;         // [64][8]
  float* redS = poolf + 8832;        // [8][8]
  int ch = blockIdx.x, n = blockIdx.y;
  int tid = threadIdx.x;
  // ---- stage 64x512B chunk (512 threads, coalesced) ----
  {
    int lane32 = tid & 31, g16 = tid >> 5;
    const unsigned* src = x + ((size_t)n * 4096 + ch * 64) * 128 + lane32 * 4;
#pragma unroll
    for (int p = 0; p < 4; ++p) {
      int row = p * 16 + g16;
      uint4 vv = *(const uint4*)(src + (size_t)row * 128);
      unsigned* dr = &xs[row * 130 + lane32 * 4];
      *(uint2*)dr = make_uint2(vv.x, vv.y);
      *(uint2*)(dr + 2) = make_uint2(vv.z, vv.w);
    }
  }
  uint4 a[8];
  if (tid < 256) {
    int l = tid & 63, g = l >> 4;
    const unsigned* ap = qwb + ((size_t)n * 8 + (l & 7)) * 128 + g * 4;
#pragma unroll
    for (int kk = 0; kk < 8; ++kk) a[kk] = *(const uint4*)(ap + kk * 16);
  }
  __syncthreads();
  // ---- QK^T via MFMA (waves 0-3; wave wv covers 16 tokens) ----
  if (tid < 256) {
    int wv = tid >> 6, l = tid & 63, col = l & 15, g = l >> 4;
    int t0 = wv * 16;
    const unsigned* xr = &xs[(t0 + col) * 130];
    f32x4 qacc = {0.f, 0.f, 0.f, 0.f};
#pragma unroll
    for (int kk = 0; kk < 8; ++kk) {
      U4B aa; aa.u = a[kk];
      U2x2B bb;
      bb.u[0] = *(const uint2*)(xr + kk * 16 + g * 4);
      bb.u[1] = *(const uint2*)(xr + kk * 16 + g * 4 + 2);
      qacc = __builtin_amdgcn_mfma_f32_16x16x32_bf16(aa.b, bb.b, qacc, 0, 0, 0);
    }
    if (g < 2) {
#pragma unroll
      for (int r = 0; r < 4; ++r) lsT[(t0 + col) * 8 + g * 4 + r] = qacc[r];
    }
  }
  __syncthreads();
  // ---- exp (no max: logits O(0.1)) + per-slot local sum (512 threads) ----
  {
    int s = tid & 7, tok = tid >> 3;  // tok 0..63
    float e0 = __expf(lsT[tok * 8 + s]);
    lsT[tok * 8 + s] = e0;
    float S = e0;
    S += __shfl_xor(S, 8);
    S += __shfl_xor(S, 16);
    S += __shfl_xor(S, 32);
    if ((tid & 63) < 8) redS[s * 8 + (tid >> 6)] = S;
  }
  __syncthreads();
  if (tid < 8) {
    float SS = 0.f;
#pragma unroll
    for (int w = 0; w < 8; ++w) SS += redS[tid * 8 + w];
    stats[((size_t)n * 8 + tid) * 64 + ch] = SS;
  }
  // ---- PV on VALU: half 0 -> slots 0-3, half 1 -> slots 4-7 ----
  {
    int half = tid >> 8, d = tid & 255;
    float pv[4] = {0, 0, 0, 0};
#pragma unroll 8
    for (int t = 0; t < 64; ++t) {
      unsigned pw = xs[t * 130 + (d >> 1)];
      float xv = (d & 1) ? bfhi(pw) : bflo(pw);
      float4 p = *(const float4*)&lsT[t * 8 + half * 4];
      pv[0] += p.x * xv; pv[1] += p.y * xv;
      pv[2] += p.z * xv; pv[3] += p.w * xv;
    }
    float* op = axp + ((size_t)n * 64 + ch) * 2048 + half * 1024 + d;
#pragma unroll
    for (int ss = 0; ss < 4; ++ss) op[ss * 256] = pv[ss];
  }
  // ---- arrival; last block of this n does the update ----
  __syncthreads();
  if (tid == 0) {
    unsigned old = __hip_atomic_fetch_add(&cnt[it * 64 + n], 1u,
                                          __ATOMIC_ACQ_REL, __HIP_MEMORY_SCOPE_AGENT);
    poolf[12319] = (old == 63u) ? 1.f : 0.f;
  }
  __syncthreads();
  if (poolf[12319] == 0.f) return;
  // ================= UPDATE (last block, 512 threads) =================
  float* ax  = poolf;
  float* sp  = poolf + 1024;
  float* upd = poolf + 2048;
  float* sn  = poolf + 3072;
  float* lnv = poolf + 4096;
  float* hid = poolf + 5120;
  float* gi  = poolf + 6144;   // [4][768]
  float* gh  = poolf + 9216;   // [4][768]
  float* red = poolf + 12288;  // [16]
  float* Sinv = poolf + 12304; // [4]
  int e = tid & 255, h = tid >> 8;
  for (int sgi = 0; sgi < 2; ++sgi) {
    int sg = sgi * 4;
    __syncthreads();
    if (tid < 4) {
      const float* st = stats + ((size_t)n * 8 + sg + tid) * 64;
      float S = 0.f;
#pragma unroll 8
      for (int c = 0; c < 64; ++c) S += st[c];
      Sinv[tid] = 1.f / (S * (1.f + 1e-8f));
    }
    __syncthreads();
    for (int i = tid; i < 1024; i += 512) {
      int sl = i >> 8, d = i & 255;
      const float* pp = axp + (size_t)n * 131072 + (sg + sl) * 256 + d;
      float acc = 0.f;
#pragma unroll 8
      for (int c = 0; c < 64; ++c) acc += pp[(size_t)c * 2048];
      ax[sl * 256 + d] = acc * Sinv[sl];
      sp[sl * 256 + d] = slots[((size_t)n * 8 + sg + sl) * 256 + d];
    }
    __syncthreads();
    {
      float a0 = 0.f, a1 = 0.f;
      for (int d = 0; d < 256; ++d) {
        float w = WvT[d * 256 + e];
        a0 += ax[(h * 2) * 256 + d] * w;
        a1 += ax[(h * 2 + 1) * 256 + d] * w;
      }
      upd[(h * 2) * 256 + e] = a0;
      upd[(h * 2 + 1) * 256 + e] = a1;
    }
    __syncthreads();
    for (int jj = tid; jj < 1536; jj += 512) {
      bool ihs = jj < 768;
      int j = ihs ? jj : jj - 768;
      const float* WT = ihs ? WihT : WhhT;
      const float* src = ihs ? upd : sp;
      float a0 = 0.f, a1 = 0.f, a2 = 0.f, a3 = 0.f;
      for (int d = 0; d < 256; ++d) {
        float w = WT[(size_t)d * 768 + j];
        a0 += src[d] * w;
        a1 += src[256 + d] * w;
        a2 += src[512 + d] * w;
        a3 += src[768 + d] * w;
      }
      float bb = ihs ? b_ih[j] : b_hh[j];
      float* dst = ihs ? gi : gh;
      dst[j] = a0 + bb;
      dst[768 + j] = a1 + bb;
      dst[1536 + j] = a2 + bb;
      dst[2304 + j] = a3 + bb;
    }
    __syncthreads();
    for (int i = tid; i < 1024; i += 512) {
      int sl = i >> 8, j = i & 255;
      float r = sigmf(gi[sl * 768 + j] + gh[sl * 768 + j]);
      float z = sigmf(gi[sl * 768 + j + 256] + gh[sl * 768 + j + 256]);
      float hh2 = tanhf(gi[sl * 768 + j + 512] + r * gh[sl * 768 + j + 512]);
      sn[sl * 256 + j] = (1.f - z) * hh2 + z * sp[sl * 256 + j];
    }
    __syncthreads();
    {
      int sl = tid >> 7, qq = tid & 127;
      float v0 = sn[sl * 256 + qq], v1 = sn[sl * 256 + qq + 128];
      float ps = wsum(v0 + v1);
      float pq = wsum(v0 * v0 + v1 * v1);
      int wid = tid >> 6;
      if ((tid & 63) == 0) { red[wid] = ps; red[8 + wid] = pq; }
      __syncthreads();
      float ssum = red[sl * 2] + red[sl * 2 + 1];
      float sqq  = red[8 + sl * 2] + red[8 + sl * 2 + 1];
      float mu = ssum * (1.f / 256.f);
      float var = sqq * (1.f / 256.f) - mu * mu;
      float rs = rsqrtf(var + 1e-5f);
      lnv[sl * 256 + qq]       = (v0 - mu) * rs * lml_g[qq] + lml_b[qq];
      lnv[sl * 256 + qq + 128] = (v1 - mu) * rs * lml_g[qq + 128] + lml_b[qq + 128];
    }
    __syncthreads();
    {
      float a0 = 0.f, a1 = 0.f;
      for (int d = 0; d < 256; ++d) {
        float w = W1T[d * 256 + e];
        a0 += lnv[(h * 2) * 256 + d] * w;
        a1 += lnv[(h * 2 + 1) * 256 + d] * w;
      }
      hid[(h * 2) * 256 + e]     = fmaxf(a0 + b1[e], 0.f);
      hid[(h * 2 + 1) * 256 + e] = fmaxf(a1 + b1[e], 0.f);
    }
    __syncthreads();
    {
      float a0 = 0.f, a1 = 0.f;
      for (int d = 0; d < 256; ++d) {
        float w = W2T[d * 256 + e];
        a0 += hid[(h * 2) * 256 + d] * w;
        a1 += hid[(h * 2 + 1) * 256 + d] * w;
      }
      float o0 = sn[(h * 2) * 256 + e] + a0 + b2[e];
      float o1 = sn[(h * 2 + 1) * 256 + e] + a1 + b2[e];
      slots[((size_t)n * 8 + sg + h * 2) * 256 + e]     = o0;
      slots[((size_t)n * 8 + sg + h * 2 + 1) * 256 + e] = o1;
      ax[(h * 2) * 256 + e] = o0;
      ax[(h * 2 + 1) * 256 + e] = o1;
    }
    if (doQw) {
      __syncthreads();
      {
        int sl = tid >> 7, qq = tid & 127;
        float v0 = ax[sl * 256 + qq], v1 = ax[sl * 256 + qq + 128];
        float ps = wsum(v0 + v1);
        float pq = wsum(v0 * v0 + v1 * v1);
        int wid = tid >> 6;
        if ((tid & 63) == 0) { red[wid] = ps; red[8 + wid] = pq; }
        __syncthreads();
        float ssum = red[sl * 2] + red[sl * 2 + 1];
        float sqq  = red[8 + sl * 2] + red[8 + sl * 2 + 1];
        float mu = ssum * (1.f / 256.f);
        float var = sqq * (1.f / 256.f) - mu * mu;
        float rs = rsqrtf(var + 1e-5f);
        sp[sl * 256 + qq]       = (v0 - mu) * rs * lsl_g[qq] + lsl_b[qq];
        sp[sl * 256 + qq + 128] = (v1 - mu) * rs * lsl_g[qq + 128] + lsl_b[qq + 128];
      }
      __syncthreads();
      {
        float a0 = 0.f, a1 = 0.f;
        for (int d = 0; d < 256; ++d) {
          float w = WqT[d * 256 + e];
          a0 += sp[(h * 2) * 256 + d] * w;
          a1 += sp[(h * 2 + 1) * 256 + d] * w;
        }
        upd[(h * 2) * 256 + e] = a0;
        upd[(h * 2 + 1) * 256 + e] = a1;
      }
      __syncthreads();
      {
        float c0 = 0.f, c1 = 0.f;
        for (int ee = 0; ee < 256; ++ee) {
          float w = Wk[(size_t)ee * 256 + e];
          c0 += upd[(h * 2) * 256 + ee] * w;
          c1 += upd[(h * 2 + 1) * 256 + ee] * w;
        }
        hid[(h * 2) * 256 + e]     = c0 * 0.0625f;
        hid[(h * 2 + 1) * 256 + e] = c1 * 0.0625f;
      }
      __syncthreads();
      {
        int sl = tid >> 7, p = tid & 127;
        qwb[((size_t)n * 8 + sg + sl) * 128 + p] =
            (unsigned)f2bf(hid[sl * 256 + 2 * p]) |
            ((unsigned)f2bf(hid[sl * 256 + 2 * p + 1]) << 16);
      }
    }
  }
}

extern "C" void kernel_launch(void* const* d_in, const int* in_sizes, int n_in,
                              void* d_out, int out_size, void* d_ws, size_t ws_size,
                              hipStream_t stream) {
  (void)in_sizes; (void)n_in; (void)out_size; (void)ws_size;
  const float* inputs = (const float*)d_in[0];
  const float* noise  = (const float*)d_in[1];
  const float* smu    = (const float*)d_in[2];
  const float* slsig  = (const float*)d_in[3];
  const float* Wq     = (const float*)d_in[4];
  const float* Wk     = (const float*)d_in[5];
  const float* Wv     = (const float*)d_in[6];
  const float* W_ih   = (const float*)d_in[7];
  const float* W_hh   = (const float*)d_in[8];
  const float* b_ih   = (const float*)d_in[9];
  const float* b_hh   = (const float*)d_in[10];
  const float* W1     = (const float*)d_in[11];
  const float* b1     = (const float*)d_in[12];
  const float* W2     = (const float*)d_in[13];
  const float* b2     = (const float*)d_in[14];
  const float* lin_g  = (const float*)d_in[15];
  const float* lin_b  = (const float*)d_in[16];
  const float* lsl_g  = (const float*)d_in[17];
  const float* lsl_b  = (const float*)d_in[18];
  const float* lml_g  = (const float*)d_in[19];
  const float* lml_b  = (const float*)d_in[20];
  float* out = (float*)d_out;
  char* ws = (char*)d_ws;
  unsigned* x    = (unsigned*)(ws + 0);            // 134217728
  unsigned* qwb  = (unsigned*)(ws + 134217728);    // 262144
  float* stats   = (float*)(ws + 134479872);       // 131072
  float* axp     = (float*)(ws + 134610944);       // 33554432
  float* WqT     = (float*)(ws + 168165376);       // 262144
  float* WvT     = (float*)(ws + 168427520);       // 262144
  float* WihT    = (float*)(ws + 168689664);       // 786432
  float* WhhT    = (float*)(ws + 169476096);       // 786432
  float* W1T     = (float*)(ws + 170262528);       // 262144
  float* W2T     = (float*)(ws + 170524672);       // 262144
  unsigned* cnt  = (unsigned*)(ws + 170786816);    // 768 (3 iters x 64 n)

  hipMemsetAsync((void*)cnt, 0, 768, stream);
  k_pre<<<dim3(66176), 256, 0, stream>>>(inputs, lin_g, lin_b, x,
                                         Wq, Wv, W_ih, W_hh, W1, W2,
                                         WqT, WvT, WihT, WhhT, W1T, W2T);
  k_qw0<<<dim3(BATCH, 8), 256, 0, stream>>>(smu, slsig, noise, lsl_g, lsl_b,
                                            WqT, Wk, out, qwb);
  for (int it = 0; it < 3; ++it) {
    k_attup<<<dim3(64, BATCH), 512, 0, stream>>>(
        x, qwb, stats, axp, cnt, it, (it < 2) ? 1 : 0,
        WvT, WihT, WhhT, b_ih, b_hh, W1T, b1, W2T, b2,
        lml_g, lml_b, lsl_g, lsl_b, WqT, Wk, out);
  }
}

// Round 15
// 388.713 us; speedup vs baseline: 7.1755x; 7.1755x over previous
//
#include <hip/hip_runtime.h>
#include <math.h>

#define TOKENS 4096
#define BATCH 64

typedef __attribute__((ext_vector_type(8))) short bf16x8;
typedef __attribute__((ext_vector_type(4))) float f32x4;
union U4B { uint4 u; bf16x8 b; };
union U2x2B { uint2 u[2]; bf16x8 b; };

__device__ __forceinline__ float wsum(float v) {
#pragma unroll
  for (int m = 32; m >= 1; m >>= 1) v += __shfl_xor(v, m);
  return v;
}
__device__ __forceinline__ unsigned short f2bf(float f) {
  unsigned u = __float_as_uint(f);
  u += 0x7fffu + ((u >> 16) & 1u);
  return (unsigned short)(u >> 16);
}
__device__ __forceinline__ float bflo(unsigned p) { return __uint_as_float(p << 16); }
__device__ __forceinline__ float bfhi(unsigned p) { return __uint_as_float(p & 0xffff0000u); }
__device__ __forceinline__ float sigmf(float x) { return 1.f / (1.f + expf(-x)); }

// ================= K_PRE: LN->x  |  weight transposes ==========
__global__ __launch_bounds__(256) void k_pre(
    const float* __restrict__ in, const float* __restrict__ lin_g,
    const float* __restrict__ lin_b, unsigned* __restrict__ x,
    const float* __restrict__ Wq, const float* __restrict__ Wv,
    const float* __restrict__ Wih, const float* __restrict__ Whh,
    const float* __restrict__ W1, const float* __restrict__ W2,
    float* __restrict__ WqT, float* __restrict__ WvT, float* __restrict__ WihT,
    float* __restrict__ WhhT, float* __restrict__ W1T, float* __restrict__ W2T) {
  int bid = blockIdx.x, tid = threadIdx.x;
  if (bid < 65536) {
    int row = bid * 4 + (tid >> 6);
    int lane = tid & 63;
    const float* p = in + (size_t)row * 256 + lane * 4;
    float4 v = *(const float4*)p;
    float s  = wsum(v.x + v.y + v.z + v.w);
    float sq = wsum(v.x * v.x + v.y * v.y + v.z * v.z + v.w * v.w);
    float mu = s * (1.f / 256.f);
    float var = sq * (1.f / 256.f) - mu * mu;
    float rs = rsqrtf(var + 1e-5f);
    float4 gg = *(const float4*)(lin_g + lane * 4);
    float4 bb = *(const float4*)(lin_b + lane * 4);
    float y0 = (v.x - mu) * rs * gg.x + bb.x;
    float y1 = (v.y - mu) * rs * gg.y + bb.y;
    float y2 = (v.z - mu) * rs * gg.z + bb.z;
    float y3 = (v.w - mu) * rs * gg.w + bb.w;
    uint2 o;
    o.x = (unsigned)f2bf(y0) | ((unsigned)f2bf(y1) << 16);
    o.y = (unsigned)f2bf(y2) | ((unsigned)f2bf(y3) << 16);
    *(uint2*)(x + (size_t)row * 128 + lane * 2) = o;
    return;
  }
  {
    __shared__ float t[32][33];
    int t2 = bid - 65536;
    const float* S; float* D; int R; int tile;
    if (t2 < 64)       { S = Wq;  D = WqT;  R = 256; tile = t2; }
    else if (t2 < 128) { S = Wv;  D = WvT;  R = 256; tile = t2 - 64; }
    else if (t2 < 192) { S = W1;  D = W1T;  R = 256; tile = t2 - 128; }
    else if (t2 < 256) { S = W2;  D = W2T;  R = 256; tile = t2 - 192; }
    else if (t2 < 448) { S = Wih; D = WihT; R = 768; tile = t2 - 256; }
    else               { S = Whh; D = WhhT; R = 768; tile = t2 - 448; }
    int rt = R >> 5;
    int r0 = (tile % rt) * 32, c0 = (tile / rt) * 32;
    int ci = tid & 31, r8 = tid >> 5;
#pragma unroll
    for (int k = 0; k < 4; ++k) {
      int r = r8 + k * 8;
      t[r][ci] = S[(size_t)(r0 + r) * 256 + c0 + ci];
    }
    __syncthreads();
#pragma unroll
    for (int k = 0; k < 4; ++k) {
      int r = r8 + k * 8;
      D[(size_t)(c0 + r) * R + r0 + ci] = t[ci][r];
    }
  }
}

// ========== K_QW0: slot init + first-iteration qw (uses WqT) ==========
__global__ __launch_bounds__(256) void k_qw0(
    const float* __restrict__ smu, const float* __restrict__ slsig,
    const float* __restrict__ noise, const float* __restrict__ lsl_g,
    const float* __restrict__ lsl_b, const float* __restrict__ WqT,
    const float* __restrict__ Wk, float* __restrict__ slots,
    unsigned* __restrict__ qwb) {
  __shared__ float ln[256];
  __shared__ float q[256];
  __shared__ float red[8];
  int n = blockIdx.x, s = blockIdx.y, tid = threadIdx.x;
  int sd = s * 256 + tid;
  float v = smu[sd] + expf(slsig[sd]) * noise[(size_t)n * 2048 + sd];
  slots[(size_t)n * 2048 + sd] = v;
  float ps = wsum(v), pq = wsum(v * v);
  if ((tid & 63) == 0) { red[tid >> 6] = ps; red[4 + (tid >> 6)] = pq; }
  __syncthreads();
  float sum = red[0] + red[1] + red[2] + red[3];
  float sqq = red[4] + red[5] + red[6] + red[7];
  float mu = sum * (1.f / 256.f);
  float var = sqq * (1.f / 256.f) - mu * mu;
  float rs = rsqrtf(var + 1e-5f);
  ln[tid] = (v - mu) * rs * lsl_g[tid] + lsl_b[tid];
  __syncthreads();
  float a = 0.f;
  for (int d = 0; d < 256; ++d) a += ln[d] * WqT[d * 256 + tid];
  q[tid] = a;
  __syncthreads();
  float c = 0.f;
  for (int e = 0; e < 256; ++e) c += q[e] * Wk[(size_t)e * 256 + tid];
  c *= 0.0625f;
  __syncthreads();
  ln[tid] = c;
  __syncthreads();
  if (tid < 128)
    qwb[((size_t)n * 8 + s) * 128 + tid] =
        (unsigned)f2bf(ln[2 * tid]) | ((unsigned)f2bf(ln[2 * tid + 1]) << 16);
}

// ========== K_ATT2: 2 chunks/block; QK^T (MFMA) + exp (no max) + PV =========
// grid (32, 64), 256 threads. Accumulates PV + S across its 2 chunks.
// Logits O(0.1) by construction -> exp without max-shift is exact.
__global__ __launch_bounds__(256) void k_att2(const unsigned* __restrict__ x,
                                              const unsigned* __restrict__ qwb,
                                              float* __restrict__ stats,
                                              float* __restrict__ axp) {
  __shared__ unsigned xs[64][130];
  __shared__ float lsT[64][8];
  __shared__ float redS[8][4];
  int bx = blockIdx.x, n = blockIdx.y;
  int tid = threadIdx.x, wv = tid >> 6, l = tid & 63;
  int col = l & 15, g = l >> 4;
  uint4 a[8];
  {
    const unsigned* ap = qwb + ((size_t)n * 8 + (l & 7)) * 128 + g * 4;
#pragma unroll
    for (int kk = 0; kk < 8; ++kk) a[kk] = *(const uint4*)(ap + kk * 16);
  }
  float pv[8] = {0, 0, 0, 0, 0, 0, 0, 0};
  float SS = 0.f;
  int s = tid & 7, tg = tid >> 3;
  for (int cc = 0; cc < 2; ++cc) {
    int ch = bx * 2 + cc;
    // stage 64x512B chunk, coalesced
    {
      int lane32 = tid & 31, g8 = tid >> 5;
      const unsigned* src = x + ((size_t)n * 4096 + ch * 64) * 128 + lane32 * 4;
#pragma unroll
      for (int p = 0; p < 8; ++p) {
        int row = p * 8 + g8;
        uint4 vv = *(const uint4*)(src + (size_t)row * 128);
        unsigned* dr = &xs[row][lane32 * 4];
        *(uint2*)dr = make_uint2(vv.x, vv.y);
        *(uint2*)(dr + 2) = make_uint2(vv.z, vv.w);
      }
    }
    __syncthreads();
    // QK^T via MFMA; wave wv covers tokens [wv*16, wv*16+16)
    {
      int t0 = wv * 16;
      const unsigned* xr = &xs[t0 + col][0];
      f32x4 qacc = {0.f, 0.f, 0.f, 0.f};
#pragma unroll
      for (int kk = 0; kk < 8; ++kk) {
        U4B aa; aa.u = a[kk];
        U2x2B bb;
        bb.u[0] = *(const uint2*)(xr + kk * 16 + g * 4);
        bb.u[1] = *(const uint2*)(xr + kk * 16 + g * 4 + 2);
        qacc = __builtin_amdgcn_mfma_f32_16x16x32_bf16(aa.b, bb.b, qacc, 0, 0, 0);
      }
      if (g < 2) {
#pragma unroll
        for (int r = 0; r < 4; ++r) lsT[t0 + col][g * 4 + r] = qacc[r];
      }
    }
    __syncthreads();
    // exp (no max) + local sum
    {
      float e0 = __expf(lsT[tg][s]);
      float e1 = __expf(lsT[tg + 32][s]);
      lsT[tg][s] = e0;
      lsT[tg + 32][s] = e1;
      float S = e0 + e1;
      S += __shfl_xor(S, 8);
      S += __shfl_xor(S, 16);
      S += __shfl_xor(S, 32);
      if (l < 8) redS[s][wv] = S;
    }
    __syncthreads();
    if (tid < 8)
      SS += redS[tid][0] + redS[tid][1] + redS[tid][2] + redS[tid][3];
    // PV on VALU; thread owns column d = tid; accumulate across chunks
    {
      int d = tid;
#pragma unroll 8
      for (int t = 0; t < 64; ++t) {
        unsigned pw = xs[t][d >> 1];
        float xv = (d & 1) ? bfhi(pw) : bflo(pw);
        float4 p0 = *(const float4*)&lsT[t][0];
        float4 p1 = *(const float4*)&lsT[t][4];
        pv[0] += p0.x * xv; pv[1] += p0.y * xv;
        pv[2] += p0.z * xv; pv[3] += p0.w * xv;
        pv[4] += p1.x * xv; pv[5] += p1.y * xv;
        pv[6] += p1.z * xv; pv[7] += p1.w * xv;
      }
    }
    __syncthreads();  // PV done before restage
  }
  if (tid < 8) stats[((size_t)n * 8 + tid) * 32 + bx] = SS;
  {
    float* op = axp + ((size_t)n * 32 + bx) * 2048 + tid;
#pragma unroll
    for (int ss = 0; ss < 8; ++ss) op[ss * 256] = pv[ss];
  }
}

// ========== K_UPDATE5: one (n,slot) per block; combine, Wv, GRU, LN, MLP ====
// grid (64, 8), 256 threads. 512 blocks -> 2x CU coverage of R13's update.
__global__ __launch_bounds__(256) void k_update5(
    const float* __restrict__ axp, const float* __restrict__ stats,
    const float* __restrict__ slots_in,
    const float* __restrict__ WvT, const float* __restrict__ WihT,
    const float* __restrict__ WhhT, const float* __restrict__ b_ih,
    const float* __restrict__ b_hh, const float* __restrict__ W1T,
    const float* __restrict__ b1, const float* __restrict__ W2T,
    const float* __restrict__ b2, const float* __restrict__ lml_g,
    const float* __restrict__ lml_b, const float* __restrict__ lsl_g,
    const float* __restrict__ lsl_b, const float* __restrict__ WqT,
    const float* __restrict__ Wk, unsigned* __restrict__ qwb, int doQw,
    float* __restrict__ slots_out) {
  __shared__ float ax[256];
  __shared__ float sp[256];
  __shared__ float upd[256];
  __shared__ float sn[256];
  __shared__ float lnv[256];
  __shared__ float hid[256];
  __shared__ float red[8];
  int n = blockIdx.x, s = blockIdx.y, tid = threadIdx.x;
  // Sinv: sum of 32 chunk sums (wave 0 reduces)
  {
    float sv = 0.f;
    if (tid < 32) sv = stats[((size_t)n * 8 + s) * 32 + tid];
    if (tid < 64) {
      sv = wsum(sv);
      if (tid == 0) red[0] = 1.f / (sv * (1.f + 1e-8f));
    }
  }
  // combine 32 chunk partials (before sync: red[0] not needed yet)
  {
    const float* pp = axp + (size_t)n * 65536 + s * 256 + tid;
    float acc = 0.f;
#pragma unroll 8
    for (int c = 0; c < 32; ++c) acc += pp[(size_t)c * 2048];
    sp[tid] = slots_in[((size_t)n * 8 + s) * 256 + tid];
    __syncthreads();
    ax[tid] = acc * red[0];
  }
  __syncthreads();
  // upd = ax @ WvT
  {
    float a0 = 0.f;
    for (int d = 0; d < 256; ++d) a0 += ax[d] * WvT[d * 256 + tid];
    upd[tid] = a0;
  }
  __syncthreads();
  // fused GRU: thread j computes r,z,n gates for this slot
  {
    int j = tid;
    float gr = 0.f, gz = 0.f, gn = 0.f, hr = 0.f, hz = 0.f, hn = 0.f;
    for (int d = 0; d < 256; ++d) {
      float u = upd[d], s_ = sp[d];
      gr += u * WihT[d * 768 + j];
      gz += u * WihT[d * 768 + j + 256];
      gn += u * WihT[d * 768 + j + 512];
      hr += s_ * WhhT[d * 768 + j];
      hz += s_ * WhhT[d * 768 + j + 256];
      hn += s_ * WhhT[d * 768 + j + 512];
    }
    float r = sigmf(gr + b_ih[j] + hr + b_hh[j]);
    float z = sigmf(gz + b_ih[j + 256] + hz + b_hh[j + 256]);
    float hh = tanhf(gn + b_ih[j + 512] + r * (hn + b_hh[j + 512]));
    sn[j] = (1.f - z) * hh + z * sp[j];
  }
  __syncthreads();
  // LN(sn) lml
  {
    float v = sn[tid];
    float ps = wsum(v), pq = wsum(v * v);
    if ((tid & 63) == 0) { red[tid >> 6] = ps; red[4 + (tid >> 6)] = pq; }
    __syncthreads();
    float sum = red[0] + red[1] + red[2] + red[3];
    float sqq = red[4] + red[5] + red[6] + red[7];
    float mu = sum * (1.f / 256.f);
    float var = sqq * (1.f / 256.f) - mu * mu;
    float rs = rsqrtf(var + 1e-5f);
    lnv[tid] = (v - mu) * rs * lml_g[tid] + lml_b[tid];
  }
  __syncthreads();
  // hid = relu(lnv @ W1T + b1)
  {
    float a0 = 0.f;
    for (int d = 0; d < 256; ++d) a0 += lnv[d] * W1T[d * 256 + tid];
    hid[tid] = fmaxf(a0 + b1[tid], 0.f);
  }
  __syncthreads();
  // out = sn + hid @ W2T + b2
  {
    float a0 = 0.f;
    for (int d = 0; d < 256; ++d) a0 += hid[d] * W2T[d * 256 + tid];
    float o = sn[tid] + a0 + b2[tid];
    slots_out[((size_t)n * 8 + s) * 256 + tid] = o;
    ax[tid] = o;
  }
  if (!doQw) return;
  __syncthreads();
  // LN(new slots) lsl -> sp
  {
    float v = ax[tid];
    float ps = wsum(v), pq = wsum(v * v);
    if ((tid & 63) == 0) { red[tid >> 6] = ps; red[4 + (tid >> 6)] = pq; }
    __syncthreads();
    float sum = red[0] + red[1] + red[2] + red[3];
    float sqq = red[4] + red[5] + red[6] + red[7];
    float mu = sum * (1.f / 256.f);
    float var = sqq * (1.f / 256.f) - mu * mu;
    float rs = rsqrtf(var + 1e-5f);
    sp[tid] = (v - mu) * rs * lsl_g[tid] + lsl_b[tid];
  }
  __syncthreads();
  {
    float a0 = 0.f;
    for (int d = 0; d < 256; ++d) a0 += sp[d] * WqT[d * 256 + tid];
    upd[tid] = a0;
  }
  __syncthreads();
  {
    float c0 = 0.f;
    for (int ee = 0; ee < 256; ++ee) c0 += upd[ee] * Wk[(size_t)ee * 256 + tid];
    hid[tid] = c0 * 0.0625f;
  }
  __syncthreads();
  if (tid < 128)
    qwb[((size_t)n * 8 + s) * 128 + tid] =
        (unsigned)f2bf(hid[2 * tid]) | ((unsigned)f2bf(hid[2 * tid + 1]) << 16);
}

extern "C" void kernel_launch(void* const* d_in, const int* in_sizes, int n_in,
                              void* d_out, int out_size, void* d_ws, size_t ws_size,
                              hipStream_t stream) {
  (void)in_sizes; (void)n_in; (void)out_size; (void)ws_size;
  const float* inputs = (const float*)d_in[0];
  const float* noise  = (const float*)d_in[1];
  const float* smu    = (const float*)d_in[2];
  const float* slsig  = (const float*)d_in[3];
  const float* Wq     = (const float*)d_in[4];
  const float* Wk     = (const float*)d_in[5];
  const float* Wv     = (const float*)d_in[6];
  const float* W_ih   = (const float*)d_in[7];
  const float* W_hh   = (const float*)d_in[8];
  const float* b_ih   = (const float*)d_in[9];
  const float* b_hh   = (const float*)d_in[10];
  const float* W1     = (const float*)d_in[11];
  const float* b1     = (const float*)d_in[12];
  const float* W2     = (const float*)d_in[13];
  const float* b2     = (const float*)d_in[14];
  const float* lin_g  = (const float*)d_in[15];
  const float* lin_b  = (const float*)d_in[16];
  const float* lsl_g  = (const float*)d_in[17];
  const float* lsl_b  = (const float*)d_in[18];
  const float* lml_g  = (const float*)d_in[19];
  const float* lml_b  = (const float*)d_in[20];
  float* out = (float*)d_out;
  char* ws = (char*)d_ws;
  unsigned* x    = (unsigned*)(ws + 0);            // 134217728
  unsigned* qwb  = (unsigned*)(ws + 134217728);    // 262144
  float* stats   = (float*)(ws + 134479872);       // 65536
  float* axp     = (float*)(ws + 134610944);       // 16777216
  float* WqT     = (float*)(ws + 168165376);       // 262144
  float* WvT     = (float*)(ws + 168427520);       // 262144
  float* WihT    = (float*)(ws + 168689664);       // 786432
  float* WhhT    = (float*)(ws + 169476096);       // 786432
  float* W1T     = (float*)(ws + 170262528);       // 262144
  float* W2T     = (float*)(ws + 170524672);       // 262144

  k_pre<<<dim3(66176), 256, 0, stream>>>(inputs, lin_g, lin_b, x,
                                         Wq, Wv, W_ih, W_hh, W1, W2,
                                         WqT, WvT, WihT, WhhT, W1T, W2T);
  k_qw0<<<dim3(BATCH, 8), 256, 0, stream>>>(smu, slsig, noise, lsl_g, lsl_b,
                                            WqT, Wk, out, qwb);
  for (int it = 0; it < 3; ++it) {
    k_att2<<<dim3(32, BATCH), 256, 0, stream>>>(x, qwb, stats, axp);
    k_update5<<<dim3(BATCH, 8), 256, 0, stream>>>(
        axp, stats, out, WvT, WihT, WhhT, b_ih, b_hh, W1T, b1, W2T, b2,
        lml_g, lml_b, lsl_g, lsl_b, WqT, Wk, qwb, (it < 2) ? 1 : 0, out);
  }
}

// Round 16
// 382.634 us; speedup vs baseline: 7.2895x; 1.0159x over previous
//
#include <hip/hip_runtime.h>
#include <math.h>

#define TOKENS 4096
#define BATCH 64

typedef __attribute__((ext_vector_type(8))) short bf16x8;
typedef __attribute__((ext_vector_type(4))) float f32x4;
union U4B { uint4 u; bf16x8 b; };
union U2x2B { uint2 u[2]; bf16x8 b; };

__device__ __forceinline__ float wsum(float v) {
#pragma unroll
  for (int m = 32; m >= 1; m >>= 1) v += __shfl_xor(v, m);
  return v;
}
__device__ __forceinline__ unsigned short f2bf(float f) {
  unsigned u = __float_as_uint(f);
  u += 0x7fffu + ((u >> 16) & 1u);
  return (unsigned short)(u >> 16);
}
__device__ __forceinline__ float bflo(unsigned p) { return __uint_as_float(p << 16); }
__device__ __forceinline__ float bfhi(unsigned p) { return __uint_as_float(p & 0xffff0000u); }
__device__ __forceinline__ float sigmf(float x) { return 1.f / (1.f + expf(-x)); }

// ================= K_PRE: LN->x  |  weight transposes ==========
__global__ __launch_bounds__(256) void k_pre(
    const float* __restrict__ in, const float* __restrict__ lin_g,
    const float* __restrict__ lin_b, unsigned* __restrict__ x,
    const float* __restrict__ Wq, const float* __restrict__ Wv,
    const float* __restrict__ Wih, const float* __restrict__ Whh,
    const float* __restrict__ W1, const float* __restrict__ W2,
    float* __restrict__ WqT, float* __restrict__ WvT, float* __restrict__ WihT,
    float* __restrict__ WhhT, float* __restrict__ W1T, float* __restrict__ W2T) {
  int bid = blockIdx.x, tid = threadIdx.x;
  if (bid < 65536) {
    int row = bid * 4 + (tid >> 6);
    int lane = tid & 63;
    const float* p = in + (size_t)row * 256 + lane * 4;
    float4 v = *(const float4*)p;
    float s  = wsum(v.x + v.y + v.z + v.w);
    float sq = wsum(v.x * v.x + v.y * v.y + v.z * v.z + v.w * v.w);
    float mu = s * (1.f / 256.f);
    float var = sq * (1.f / 256.f) - mu * mu;
    float rs = rsqrtf(var + 1e-5f);
    float4 gg = *(const float4*)(lin_g + lane * 4);
    float4 bb = *(const float4*)(lin_b + lane * 4);
    float y0 = (v.x - mu) * rs * gg.x + bb.x;
    float y1 = (v.y - mu) * rs * gg.y + bb.y;
    float y2 = (v.z - mu) * rs * gg.z + bb.z;
    float y3 = (v.w - mu) * rs * gg.w + bb.w;
    uint2 o;
    o.x = (unsigned)f2bf(y0) | ((unsigned)f2bf(y1) << 16);
    o.y = (unsigned)f2bf(y2) | ((unsigned)f2bf(y3) << 16);
    *(uint2*)(x + (size_t)row * 128 + lane * 2) = o;
    return;
  }
  {
    __shared__ float t[32][33];
    int t2 = bid - 65536;
    const float* S; float* D; int R; int tile;
    if (t2 < 64)       { S = Wq;  D = WqT;  R = 256; tile = t2; }
    else if (t2 < 128) { S = Wv;  D = WvT;  R = 256; tile = t2 - 64; }
    else if (t2 < 192) { S = W1;  D = W1T;  R = 256; tile = t2 - 128; }
    else if (t2 < 256) { S = W2;  D = W2T;  R = 256; tile = t2 - 192; }
    else if (t2 < 448) { S = Wih; D = WihT; R = 768; tile = t2 - 256; }
    else               { S = Whh; D = WhhT; R = 768; tile = t2 - 448; }
    int rt = R >> 5;
    int r0 = (tile % rt) * 32, c0 = (tile / rt) * 32;
    int ci = tid & 31, r8 = tid >> 5;
#pragma unroll
    for (int k = 0; k < 4; ++k) {
      int r = r8 + k * 8;
      t[r][ci] = S[(size_t)(r0 + r) * 256 + c0 + ci];
    }
    __syncthreads();
#pragma unroll
    for (int k = 0; k < 4; ++k) {
      int r = r8 + k * 8;
      D[(size_t)(c0 + r) * R + r0 + ci] = t[ci][r];
    }
  }
}

// ========== K_QW0: slot init + first-iteration qw (uses WqT) ==========
__global__ __launch_bounds__(256) void k_qw0(
    const float* __restrict__ smu, const float* __restrict__ slsig,
    const float* __restrict__ noise, const float* __restrict__ lsl_g,
    const float* __restrict__ lsl_b, const float* __restrict__ WqT,
    const float* __restrict__ Wk, float* __restrict__ slots,
    unsigned* __restrict__ qwb) {
  __shared__ float ln[256];
  __shared__ float q[256];
  __shared__ float red[8];
  int n = blockIdx.x, s = blockIdx.y, tid = threadIdx.x;
  int sd = s * 256 + tid;
  float v = smu[sd] + expf(slsig[sd]) * noise[(size_t)n * 2048 + sd];
  slots[(size_t)n * 2048 + sd] = v;
  float ps = wsum(v), pq = wsum(v * v);
  if ((tid & 63) == 0) { red[tid >> 6] = ps; red[4 + (tid >> 6)] = pq; }
  __syncthreads();
  float sum = red[0] + red[1] + red[2] + red[3];
  float sqq = red[4] + red[5] + red[6] + red[7];
  float mu = sum * (1.f / 256.f);
  float var = sqq * (1.f / 256.f) - mu * mu;
  float rs = rsqrtf(var + 1e-5f);
  ln[tid] = (v - mu) * rs * lsl_g[tid] + lsl_b[tid];
  __syncthreads();
  float a = 0.f;
  for (int d = 0; d < 256; ++d) a += ln[d] * WqT[d * 256 + tid];
  q[tid] = a;
  __syncthreads();
  float c = 0.f;
  for (int e = 0; e < 256; ++e) c += q[e] * Wk[(size_t)e * 256 + tid];
  c *= 0.0625f;
  __syncthreads();
  ln[tid] = c;
  __syncthreads();
  if (tid < 128)
    qwb[((size_t)n * 8 + s) * 128 + tid] =
        (unsigned)f2bf(ln[2 * tid]) | ((unsigned)f2bf(ln[2 * tid + 1]) << 16);
}

// ========== K_ATT4: 4 chunks/block; QK^T (MFMA) + exp (no max) + PV =========
// grid (16, 64), 256 threads. Accumulates PV + S across its 4 chunks.
// Logits O(0.1) by construction -> exp without max-shift is exact.
__global__ __launch_bounds__(256) void k_att4(const unsigned* __restrict__ x,
                                              const unsigned* __restrict__ qwb,
                                              float* __restrict__ stats,
                                              float* __restrict__ axp) {
  __shared__ unsigned xs[64][130];
  __shared__ float lsT[64][8];
  __shared__ float redS[8][4];
  int bx = blockIdx.x, n = blockIdx.y;
  int tid = threadIdx.x, wv = tid >> 6, l = tid & 63;
  int col = l & 15, g = l >> 4;
  uint4 a[8];
  {
    const unsigned* ap = qwb + ((size_t)n * 8 + (l & 7)) * 128 + g * 4;
#pragma unroll
    for (int kk = 0; kk < 8; ++kk) a[kk] = *(const uint4*)(ap + kk * 16);
  }
  float pv[8] = {0, 0, 0, 0, 0, 0, 0, 0};
  float SS = 0.f;
  int s = tid & 7, tg = tid >> 3;
  for (int cc = 0; cc < 4; ++cc) {
    int ch = bx * 4 + cc;
    // stage 64x512B chunk, coalesced
    {
      int lane32 = tid & 31, g8 = tid >> 5;
      const unsigned* src = x + ((size_t)n * 4096 + ch * 64) * 128 + lane32 * 4;
#pragma unroll
      for (int p = 0; p < 8; ++p) {
        int row = p * 8 + g8;
        uint4 vv = *(const uint4*)(src + (size_t)row * 128);
        unsigned* dr = &xs[row][lane32 * 4];
        *(uint2*)dr = make_uint2(vv.x, vv.y);
        *(uint2*)(dr + 2) = make_uint2(vv.z, vv.w);
      }
    }
    __syncthreads();
    // QK^T via MFMA; wave wv covers tokens [wv*16, wv*16+16)
    {
      int t0 = wv * 16;
      const unsigned* xr = &xs[t0 + col][0];
      f32x4 qacc = {0.f, 0.f, 0.f, 0.f};
#pragma unroll
      for (int kk = 0; kk < 8; ++kk) {
        U4B aa; aa.u = a[kk];
        U2x2B bb;
        bb.u[0] = *(const uint2*)(xr + kk * 16 + g * 4);
        bb.u[1] = *(const uint2*)(xr + kk * 16 + g * 4 + 2);
        qacc = __builtin_amdgcn_mfma_f32_16x16x32_bf16(aa.b, bb.b, qacc, 0, 0, 0);
      }
      if (g < 2) {
#pragma unroll
        for (int r = 0; r < 4; ++r) lsT[t0 + col][g * 4 + r] = qacc[r];
      }
    }
    __syncthreads();
    // exp (no max) + local sum
    {
      float e0 = __expf(lsT[tg][s]);
      float e1 = __expf(lsT[tg + 32][s]);
      lsT[tg][s] = e0;
      lsT[tg + 32][s] = e1;
      float S = e0 + e1;
      S += __shfl_xor(S, 8);
      S += __shfl_xor(S, 16);
      S += __shfl_xor(S, 32);
      if (l < 8) redS[s][wv] = S;
    }
    __syncthreads();
    if (tid < 8)
      SS += redS[tid][0] + redS[tid][1] + redS[tid][2] + redS[tid][3];
    // PV on VALU; thread owns column d = tid; accumulate across chunks
    {
      int d = tid;
#pragma unroll 8
      for (int t = 0; t < 64; ++t) {
        unsigned pw = xs[t][d >> 1];
        float xv = (d & 1) ? bfhi(pw) : bflo(pw);
        float4 p0 = *(const float4*)&lsT[t][0];
        float4 p1 = *(const float4*)&lsT[t][4];
        pv[0] += p0.x * xv; pv[1] += p0.y * xv;
        pv[2] += p0.z * xv; pv[3] += p0.w * xv;
        pv[4] += p1.x * xv; pv[5] += p1.y * xv;
        pv[6] += p1.z * xv; pv[7] += p1.w * xv;
      }
    }
    __syncthreads();  // PV done before restage
  }
  if (tid < 8) stats[((size_t)n * 8 + tid) * 16 + bx] = SS;
  {
    float* op = axp + ((size_t)n * 16 + bx) * 2048 + tid;
#pragma unroll
    for (int ss = 0; ss < 8; ++ss) op[ss * 256] = pv[ss];
  }
}

// ========== K_UPDATE5: one (n,slot) per block; combine, Wv, GRU, LN, MLP ====
// grid (64, 8), 256 threads.
__global__ __launch_bounds__(256) void k_update5(
    const float* __restrict__ axp, const float* __restrict__ stats,
    const float* __restrict__ slots_in,
    const float* __restrict__ WvT, const float* __restrict__ WihT,
    const float* __restrict__ WhhT, const float* __restrict__ b_ih,
    const float* __restrict__ b_hh, const float* __restrict__ W1T,
    const float* __restrict__ b1, const float* __restrict__ W2T,
    const float* __restrict__ b2, const float* __restrict__ lml_g,
    const float* __restrict__ lml_b, const float* __restrict__ lsl_g,
    const float* __restrict__ lsl_b, const float* __restrict__ WqT,
    const float* __restrict__ Wk, unsigned* __restrict__ qwb, int doQw,
    float* __restrict__ slots_out) {
  __shared__ float ax[256];
  __shared__ float sp[256];
  __shared__ float upd[256];
  __shared__ float sn[256];
  __shared__ float lnv[256];
  __shared__ float hid[256];
  __shared__ float red[8];
  int n = blockIdx.x, s = blockIdx.y, tid = threadIdx.x;
  // Sinv: sum of 16 chunk sums (wave 0 reduces)
  {
    float sv = 0.f;
    if (tid < 16) sv = stats[((size_t)n * 8 + s) * 16 + tid];
    if (tid < 64) {
      sv = wsum(sv);
      if (tid == 0) red[0] = 1.f / (sv * (1.f + 1e-8f));
    }
  }
  // combine 16 chunk partials
  {
    const float* pp = axp + (size_t)n * 32768 + s * 256 + tid;
    float acc = 0.f;
#pragma unroll 8
    for (int c = 0; c < 16; ++c) acc += pp[(size_t)c * 2048];
    sp[tid] = slots_in[((size_t)n * 8 + s) * 256 + tid];
    __syncthreads();
    ax[tid] = acc * red[0];
  }
  __syncthreads();
  // upd = ax @ WvT
  {
    float a0 = 0.f;
    for (int d = 0; d < 256; ++d) a0 += ax[d] * WvT[d * 256 + tid];
    upd[tid] = a0;
  }
  __syncthreads();
  // fused GRU: thread j computes r,z,n gates for this slot
  {
    int j = tid;
    float gr = 0.f, gz = 0.f, gn = 0.f, hr = 0.f, hz = 0.f, hn = 0.f;
    for (int d = 0; d < 256; ++d) {
      float u = upd[d], s_ = sp[d];
      gr += u * WihT[d * 768 + j];
      gz += u * WihT[d * 768 + j + 256];
      gn += u * WihT[d * 768 + j + 512];
      hr += s_ * WhhT[d * 768 + j];
      hz += s_ * WhhT[d * 768 + j + 256];
      hn += s_ * WhhT[d * 768 + j + 512];
    }
    float r = sigmf(gr + b_ih[j] + hr + b_hh[j]);
    float z = sigmf(gz + b_ih[j + 256] + hz + b_hh[j + 256]);
    float hh = tanhf(gn + b_ih[j + 512] + r * (hn + b_hh[j + 512]));
    sn[j] = (1.f - z) * hh + z * sp[j];
  }
  __syncthreads();
  // LN(sn) lml
  {
    float v = sn[tid];
    float ps = wsum(v), pq = wsum(v * v);
    if ((tid & 63) == 0) { red[tid >> 6] = ps; red[4 + (tid >> 6)] = pq; }
    __syncthreads();
    float sum = red[0] + red[1] + red[2] + red[3];
    float sqq = red[4] + red[5] + red[6] + red[7];
    float mu = sum * (1.f / 256.f);
    float var = sqq * (1.f / 256.f) - mu * mu;
    float rs = rsqrtf(var + 1e-5f);
    lnv[tid] = (v - mu) * rs * lml_g[tid] + lml_b[tid];
  }
  __syncthreads();
  // hid = relu(lnv @ W1T + b1)
  {
    float a0 = 0.f;
    for (int d = 0; d < 256; ++d) a0 += lnv[d] * W1T[d * 256 + tid];
    hid[tid] = fmaxf(a0 + b1[tid], 0.f);
  }
  __syncthreads();
  // out = sn + hid @ W2T + b2
  {
    float a0 = 0.f;
    for (int d = 0; d < 256; ++d) a0 += hid[d] * W2T[d * 256 + tid];
    float o = sn[tid] + a0 + b2[tid];
    slots_out[((size_t)n * 8 + s) * 256 + tid] = o;
    ax[tid] = o;
  }
  if (!doQw) return;
  __syncthreads();
  // LN(new slots) lsl -> sp
  {
    float v = ax[tid];
    float ps = wsum(v), pq = wsum(v * v);
    if ((tid & 63) == 0) { red[tid >> 6] = ps; red[4 + (tid >> 6)] = pq; }
    __syncthreads();
    float sum = red[0] + red[1] + red[2] + red[3];
    float sqq = red[4] + red[5] + red[6] + red[7];
    float mu = sum * (1.f / 256.f);
    float var = sqq * (1.f / 256.f) - mu * mu;
    float rs = rsqrtf(var + 1e-5f);
    sp[tid] = (v - mu) * rs * lsl_g[tid] + lsl_b[tid];
  }
  __syncthreads();
  {
    float a0 = 0.f;
    for (int d = 0; d < 256; ++d) a0 += sp[d] * WqT[d * 256 + tid];
    upd[tid] = a0;
  }
  __syncthreads();
  {
    float c0 = 0.f;
    for (int ee = 0; ee < 256; ++ee) c0 += upd[ee] * Wk[(size_t)ee * 256 + tid];
    hid[tid] = c0 * 0.0625f;
  }
  __syncthreads();
  if (tid < 128)
    qwb[((size_t)n * 8 + s) * 128 + tid] =
        (unsigned)f2bf(hid[2 * tid]) | ((unsigned)f2bf(hid[2 * tid + 1]) << 16);
}

extern "C" void kernel_launch(void* const* d_in, const int* in_sizes, int n_in,
                              void* d_out, int out_size, void* d_ws, size_t ws_size,
                              hipStream_t stream) {
  (void)in_sizes; (void)n_in; (void)out_size; (void)ws_size;
  const float* inputs = (const float*)d_in[0];
  const float* noise  = (const float*)d_in[1];
  const float* smu    = (const float*)d_in[2];
  const float* slsig  = (const float*)d_in[3];
  const float* Wq     = (const float*)d_in[4];
  const float* Wk     = (const float*)d_in[5];
  const float* Wv     = (const float*)d_in[6];
  const float* W_ih   = (const float*)d_in[7];
  const float* W_hh   = (const float*)d_in[8];
  const float* b_ih   = (const float*)d_in[9];
  const float* b_hh   = (const float*)d_in[10];
  const float* W1     = (const float*)d_in[11];
  const float* b1     = (const float*)d_in[12];
  const float* W2     = (const float*)d_in[13];
  const float* b2     = (const float*)d_in[14];
  const float* lin_g  = (const float*)d_in[15];
  const float* lin_b  = (const float*)d_in[16];
  const float* lsl_g  = (const float*)d_in[17];
  const float* lsl_b  = (const float*)d_in[18];
  const float* lml_g  = (const float*)d_in[19];
  const float* lml_b  = (const float*)d_in[20];
  float* out = (float*)d_out;
  char* ws = (char*)d_ws;
  unsigned* x    = (unsigned*)(ws + 0);            // 134217728
  unsigned* qwb  = (unsigned*)(ws + 134217728);    // 262144
  float* stats   = (float*)(ws + 134479872);       // 32768
  float* axp     = (float*)(ws + 134610944);       // 8388608
  float* WqT     = (float*)(ws + 168165376);       // 262144
  float* WvT     = (float*)(ws + 168427520);       // 262144
  float* WihT    = (float*)(ws + 168689664);       // 786432
  float* WhhT    = (float*)(ws + 169476096);       // 786432
  float* W1T     = (float*)(ws + 170262528);       // 262144
  float* W2T     = (float*)(ws + 170524672);       // 262144

  k_pre<<<dim3(66176), 256, 0, stream>>>(inputs, lin_g, lin_b, x,
                                         Wq, Wv, W_ih, W_hh, W1, W2,
                                         WqT, WvT, WihT, WhhT, W1T, W2T);
  k_qw0<<<dim3(BATCH, 8), 256, 0, stream>>>(smu, slsig, noise, lsl_g, lsl_b,
                                            WqT, Wk, out, qwb);
  for (int it = 0; it < 3; ++it) {
    k_att4<<<dim3(16, BATCH), 256, 0, stream>>>(x, qwb, stats, axp);
    k_update5<<<dim3(BATCH, 8), 256, 0, stream>>>(
        axp, stats, out, WvT, WihT, WhhT, b_ih, b_hh, W1T, b1, W2T, b2,
        lml_g, lml_b, lsl_g, lsl_b, WqT, Wk, qwb, (it < 2) ? 1 : 0, out);
  }
}

// Round 17
// 381.916 us; speedup vs baseline: 7.3032x; 1.0019x over previous
//
#include <hip/hip_runtime.h>
#include <math.h>

#define TOKENS 4096
#define BATCH 64

typedef __attribute__((ext_vector_type(8))) short bf16x8;
typedef __attribute__((ext_vector_type(4))) float f32x4;
union U4B { uint4 u; bf16x8 b; };
union U2x2B { uint2 u[2]; bf16x8 b; };

__device__ __forceinline__ float wsum(float v) {
#pragma unroll
  for (int m = 32; m >= 1; m >>= 1) v += __shfl_xor(v, m);
  return v;
}
__device__ __forceinline__ unsigned short f2bf(float f) {
  unsigned u = __float_as_uint(f);
  u += 0x7fffu + ((u >> 16) & 1u);
  return (unsigned short)(u >> 16);
}
__device__ __forceinline__ float bflo(unsigned p) { return __uint_as_float(p << 16); }
__device__ __forceinline__ float bfhi(unsigned p) { return __uint_as_float(p & 0xffff0000u); }
__device__ __forceinline__ float sigmf(float x) { return 1.f / (1.f + expf(-x)); }

// ================= K_PRE: LN->x  |  weight transposes ==========
__global__ __launch_bounds__(256) void k_pre(
    const float* __restrict__ in, const float* __restrict__ lin_g,
    const float* __restrict__ lin_b, unsigned* __restrict__ x,
    const float* __restrict__ Wq, const float* __restrict__ Wv,
    const float* __restrict__ Wih, const float* __restrict__ Whh,
    const float* __restrict__ W1, const float* __restrict__ W2,
    float* __restrict__ WqT, float* __restrict__ WvT, float* __restrict__ WihT,
    float* __restrict__ WhhT, float* __restrict__ W1T, float* __restrict__ W2T) {
  int bid = blockIdx.x, tid = threadIdx.x;
  if (bid < 65536) {
    int row = bid * 4 + (tid >> 6);
    int lane = tid & 63;
    const float* p = in + (size_t)row * 256 + lane * 4;
    float4 v = *(const float4*)p;
    float s  = wsum(v.x + v.y + v.z + v.w);
    float sq = wsum(v.x * v.x + v.y * v.y + v.z * v.z + v.w * v.w);
    float mu = s * (1.f / 256.f);
    float var = sq * (1.f / 256.f) - mu * mu;
    float rs = rsqrtf(var + 1e-5f);
    float4 gg = *(const float4*)(lin_g + lane * 4);
    float4 bb = *(const float4*)(lin_b + lane * 4);
    float y0 = (v.x - mu) * rs * gg.x + bb.x;
    float y1 = (v.y - mu) * rs * gg.y + bb.y;
    float y2 = (v.z - mu) * rs * gg.z + bb.z;
    float y3 = (v.w - mu) * rs * gg.w + bb.w;
    uint2 o;
    o.x = (unsigned)f2bf(y0) | ((unsigned)f2bf(y1) << 16);
    o.y = (unsigned)f2bf(y2) | ((unsigned)f2bf(y3) << 16);
    *(uint2*)(x + (size_t)row * 128 + lane * 2) = o;
    return;
  }
  {
    __shared__ float t[32][33];
    int t2 = bid - 65536;
    const float* S; float* D; int R; int tile;
    if (t2 < 64)       { S = Wq;  D = WqT;  R = 256; tile = t2; }
    else if (t2 < 128) { S = Wv;  D = WvT;  R = 256; tile = t2 - 64; }
    else if (t2 < 192) { S = W1;  D = W1T;  R = 256; tile = t2 - 128; }
    else if (t2 < 256) { S = W2;  D = W2T;  R = 256; tile = t2 - 192; }
    else if (t2 < 448) { S = Wih; D = WihT; R = 768; tile = t2 - 256; }
    else               { S = Whh; D = WhhT; R = 768; tile = t2 - 448; }
    int rt = R >> 5;
    int r0 = (tile % rt) * 32, c0 = (tile / rt) * 32;
    int ci = tid & 31, r8 = tid >> 5;
#pragma unroll
    for (int k = 0; k < 4; ++k) {
      int r = r8 + k * 8;
      t[r][ci] = S[(size_t)(r0 + r) * 256 + c0 + ci];
    }
    __syncthreads();
#pragma unroll
    for (int k = 0; k < 4; ++k) {
      int r = r8 + k * 8;
      D[(size_t)(c0 + r) * R + r0 + ci] = t[ci][r];
    }
  }
}

// ========== K_QW0: slot init + first-iteration qw (uses WqT) ==========
__global__ __launch_bounds__(256) void k_qw0(
    const float* __restrict__ smu, const float* __restrict__ slsig,
    const float* __restrict__ noise, const float* __restrict__ lsl_g,
    const float* __restrict__ lsl_b, const float* __restrict__ WqT,
    const float* __restrict__ Wk, float* __restrict__ slots,
    unsigned* __restrict__ qwb) {
  __shared__ float ln[256];
  __shared__ float q[256];
  __shared__ float red[8];
  int n = blockIdx.x, s = blockIdx.y, tid = threadIdx.x;
  int sd = s * 256 + tid;
  float v = smu[sd] + expf(slsig[sd]) * noise[(size_t)n * 2048 + sd];
  slots[(size_t)n * 2048 + sd] = v;
  float ps = wsum(v), pq = wsum(v * v);
  if ((tid & 63) == 0) { red[tid >> 6] = ps; red[4 + (tid >> 6)] = pq; }
  __syncthreads();
  float sum = red[0] + red[1] + red[2] + red[3];
  float sqq = red[4] + red[5] + red[6] + red[7];
  float mu = sum * (1.f / 256.f);
  float var = sqq * (1.f / 256.f) - mu * mu;
  float rs = rsqrtf(var + 1e-5f);
  ln[tid] = (v - mu) * rs * lsl_g[tid] + lsl_b[tid];
  __syncthreads();
  float a = 0.f;
  for (int d = 0; d < 256; ++d) a += ln[d] * WqT[d * 256 + tid];
  q[tid] = a;
  __syncthreads();
  float c = 0.f;
  for (int e = 0; e < 256; ++e) c += q[e] * Wk[(size_t)e * 256 + tid];
  c *= 0.0625f;
  __syncthreads();
  ln[tid] = c;
  __syncthreads();
  if (tid < 128)
    qwb[((size_t)n * 8 + s) * 128 + tid] =
        (unsigned)f2bf(ln[2 * tid]) | ((unsigned)f2bf(ln[2 * tid + 1]) << 16);
}

// ========== K_ATT4P: 4 chunks/block with register-prefetch double buffer ====
// grid (16, 64), 256 threads. QK^T (MFMA) + exp (no max) + PV (VALU).
// Next chunk's loads are issued into registers right after the stage-read
// sync, so L3/HBM latency hides under MFMA+exp+PV of the current chunk.
__global__ __launch_bounds__(256) void k_att4p(const unsigned* __restrict__ x,
                                               const unsigned* __restrict__ qwb,
                                               float* __restrict__ stats,
                                               float* __restrict__ axp) {
  __shared__ unsigned xs[64][130];
  __shared__ float lsT[64][8];
  __shared__ float redS[8][4];
  int bx = blockIdx.x, n = blockIdx.y;
  int tid = threadIdx.x, wv = tid >> 6, l = tid & 63;
  int col = l & 15, g = l >> 4;
  int lane32 = tid & 31, g8 = tid >> 5;
  uint4 a[8];
  {
    const unsigned* ap = qwb + ((size_t)n * 8 + (l & 7)) * 128 + g * 4;
#pragma unroll
    for (int kk = 0; kk < 8; ++kk) a[kk] = *(const uint4*)(ap + kk * 16);
  }
  float pv[8] = {0, 0, 0, 0, 0, 0, 0, 0};
  float SS = 0.f;
  int s = tid & 7, tg = tid >> 3;
  const unsigned* base = x + ((size_t)n * 4096 + bx * 256) * 128 + lane32 * 4;
  uint4 st[8];
  // stage chunk 0 directly into LDS
#pragma unroll
  for (int p = 0; p < 8; ++p)
    st[p] = *(const uint4*)(base + (size_t)(p * 8 + g8) * 128);
#pragma unroll
  for (int p = 0; p < 8; ++p) {
    unsigned* dr = &xs[p * 8 + g8][lane32 * 4];
    *(uint2*)dr = make_uint2(st[p].x, st[p].y);
    *(uint2*)(dr + 2) = make_uint2(st[p].z, st[p].w);
  }
  __syncthreads();
  for (int cc = 0; cc < 4; ++cc) {
    // issue next chunk's loads into registers (latency hidden under compute)
    if (cc < 3) {
      const unsigned* src = base + (size_t)(cc + 1) * 64 * 128;
#pragma unroll
      for (int p = 0; p < 8; ++p)
        st[p] = *(const uint4*)(src + (size_t)(p * 8 + g8) * 128);
    }
    // QK^T via MFMA; wave wv covers tokens [wv*16, wv*16+16)
    {
      int t0 = wv * 16;
      const unsigned* xr = &xs[t0 + col][0];
      f32x4 qacc = {0.f, 0.f, 0.f, 0.f};
#pragma unroll
      for (int kk = 0; kk < 8; ++kk) {
        U4B aa; aa.u = a[kk];
        U2x2B bb;
        bb.u[0] = *(const uint2*)(xr + kk * 16 + g * 4);
        bb.u[1] = *(const uint2*)(xr + kk * 16 + g * 4 + 2);
        qacc = __builtin_amdgcn_mfma_f32_16x16x32_bf16(aa.b, bb.b, qacc, 0, 0, 0);
      }
      if (g < 2) {
#pragma unroll
        for (int r = 0; r < 4; ++r) lsT[t0 + col][g * 4 + r] = qacc[r];
      }
    }
    __syncthreads();
    // exp (no max: logits O(0.1) by construction) + local sum
    {
      float e0 = __expf(lsT[tg][s]);
      float e1 = __expf(lsT[tg + 32][s]);
      lsT[tg][s] = e0;
      lsT[tg + 32][s] = e1;
      float S = e0 + e1;
      S += __shfl_xor(S, 8);
      S += __shfl_xor(S, 16);
      S += __shfl_xor(S, 32);
      if (l < 8) redS[s][wv] = S;
    }
    __syncthreads();
    if (tid < 8)
      SS += redS[tid][0] + redS[tid][1] + redS[tid][2] + redS[tid][3];
    // PV on VALU; thread owns column d = tid; accumulate across chunks
    {
      int d = tid;
#pragma unroll 8
      for (int t = 0; t < 64; ++t) {
        unsigned pw = xs[t][d >> 1];
        float xv = (d & 1) ? bfhi(pw) : bflo(pw);
        float4 p0 = *(const float4*)&lsT[t][0];
        float4 p1 = *(const float4*)&lsT[t][4];
        pv[0] += p0.x * xv; pv[1] += p0.y * xv;
        pv[2] += p0.z * xv; pv[3] += p0.w * xv;
        pv[4] += p1.x * xv; pv[5] += p1.y * xv;
        pv[6] += p1.z * xv; pv[7] += p1.w * xv;
      }
    }
    __syncthreads();  // all reads of xs done
    // commit prefetched chunk to LDS
    if (cc < 3) {
#pragma unroll
      for (int p = 0; p < 8; ++p) {
        unsigned* dr = &xs[p * 8 + g8][lane32 * 4];
        *(uint2*)dr = make_uint2(st[p].x, st[p].y);
        *(uint2*)(dr + 2) = make_uint2(st[p].z, st[p].w);
      }
      __syncthreads();
    }
  }
  if (tid < 8) stats[((size_t)n * 8 + tid) * 16 + bx] = SS;
  {
    float* op = axp + ((size_t)n * 16 + bx) * 2048 + tid;
#pragma unroll
    for (int ss = 0; ss < 8; ++ss) op[ss * 256] = pv[ss];
  }
}

// ========== K_UPDATE5: one (n,slot) per block; combine, Wv, GRU, LN, MLP ====
// grid (64, 8), 256 threads.
__global__ __launch_bounds__(256) void k_update5(
    const float* __restrict__ axp, const float* __restrict__ stats,
    const float* __restrict__ slots_in,
    const float* __restrict__ WvT, const float* __restrict__ WihT,
    const float* __restrict__ WhhT, const float* __restrict__ b_ih,
    const float* __restrict__ b_hh, const float* __restrict__ W1T,
    const float* __restrict__ b1, const float* __restrict__ W2T,
    const float* __restrict__ b2, const float* __restrict__ lml_g,
    const float* __restrict__ lml_b, const float* __restrict__ lsl_g,
    const float* __restrict__ lsl_b, const float* __restrict__ WqT,
    const float* __restrict__ Wk, unsigned* __restrict__ qwb, int doQw,
    float* __restrict__ slots_out) {
  __shared__ float ax[256];
  __shared__ float sp[256];
  __shared__ float upd[256];
  __shared__ float sn[256];
  __shared__ float lnv[256];
  __shared__ float hid[256];
  __shared__ float red[8];
  int n = blockIdx.x, s = blockIdx.y, tid = threadIdx.x;
  // Sinv: sum of 16 chunk sums (wave 0 reduces)
  {
    float sv = 0.f;
    if (tid < 16) sv = stats[((size_t)n * 8 + s) * 16 + tid];
    if (tid < 64) {
      sv = wsum(sv);
      if (tid == 0) red[0] = 1.f / (sv * (1.f + 1e-8f));
    }
  }
  // combine 16 chunk partials
  {
    const float* pp = axp + (size_t)n * 32768 + s * 256 + tid;
    float acc = 0.f;
#pragma unroll 8
    for (int c = 0; c < 16; ++c) acc += pp[(size_t)c * 2048];
    sp[tid] = slots_in[((size_t)n * 8 + s) * 256 + tid];
    __syncthreads();
    ax[tid] = acc * red[0];
  }
  __syncthreads();
  // upd = ax @ WvT
  {
    float a0 = 0.f;
    for (int d = 0; d < 256; ++d) a0 += ax[d] * WvT[d * 256 + tid];
    upd[tid] = a0;
  }
  __syncthreads();
  // fused GRU: thread j computes r,z,n gates for this slot
  {
    int j = tid;
    float gr = 0.f, gz = 0.f, gn = 0.f, hr = 0.f, hz = 0.f, hn = 0.f;
    for (int d = 0; d < 256; ++d) {
      float u = upd[d], s_ = sp[d];
      gr += u * WihT[d * 768 + j];
      gz += u * WihT[d * 768 + j + 256];
      gn += u * WihT[d * 768 + j + 512];
      hr += s_ * WhhT[d * 768 + j];
      hz += s_ * WhhT[d * 768 + j + 256];
      hn += s_ * WhhT[d * 768 + j + 512];
    }
    float r = sigmf(gr + b_ih[j] + hr + b_hh[j]);
    float z = sigmf(gz + b_ih[j + 256] + hz + b_hh[j + 256]);
    float hh = tanhf(gn + b_ih[j + 512] + r * (hn + b_hh[j + 512]));
    sn[j] = (1.f - z) * hh + z * sp[j];
  }
  __syncthreads();
  // LN(sn) lml
  {
    float v = sn[tid];
    float ps = wsum(v), pq = wsum(v * v);
    if ((tid & 63) == 0) { red[tid >> 6] = ps; red[4 + (tid >> 6)] = pq; }
    __syncthreads();
    float sum = red[0] + red[1] + red[2] + red[3];
    float sqq = red[4] + red[5] + red[6] + red[7];
    float mu = sum * (1.f / 256.f);
    float var = sqq * (1.f / 256.f) - mu * mu;
    float rs = rsqrtf(var + 1e-5f);
    lnv[tid] = (v - mu) * rs * lml_g[tid] + lml_b[tid];
  }
  __syncthreads();
  // hid = relu(lnv @ W1T + b1)
  {
    float a0 = 0.f;
    for (int d = 0; d < 256; ++d) a0 += lnv[d] * W1T[d * 256 + tid];
    hid[tid] = fmaxf(a0 + b1[tid], 0.f);
  }
  __syncthreads();
  // out = sn + hid @ W2T + b2
  {
    float a0 = 0.f;
    for (int d = 0; d < 256; ++d) a0 += hid[d] * W2T[d * 256 + tid];
    float o = sn[tid] + a0 + b2[tid];
    slots_out[((size_t)n * 8 + s) * 256 + tid] = o;
    ax[tid] = o;
  }
  if (!doQw) return;
  __syncthreads();
  // LN(new slots) lsl -> sp
  {
    float v = ax[tid];
    float ps = wsum(v), pq = wsum(v * v);
    if ((tid & 63) == 0) { red[tid >> 6] = ps; red[4 + (tid >> 6)] = pq; }
    __syncthreads();
    float sum = red[0] + red[1] + red[2] + red[3];
    float sqq = red[4] + red[5] + red[6] + red[7];
    float mu = sum * (1.f / 256.f);
    float var = sqq * (1.f / 256.f) - mu * mu;
    float rs = rsqrtf(var + 1e-5f);
    sp[tid] = (v - mu) * rs * lsl_g[tid] + lsl_b[tid];
  }
  __syncthreads();
  {
    float a0 = 0.f;
    for (int d = 0; d < 256; ++d) a0 += sp[d] * WqT[d * 256 + tid];
    upd[tid] = a0;
  }
  __syncthreads();
  {
    float c0 = 0.f;
    for (int ee = 0; ee < 256; ++ee) c0 += upd[ee] * Wk[(size_t)ee * 256 + tid];
    hid[tid] = c0 * 0.0625f;
  }
  __syncthreads();
  if (tid < 128)
    qwb[((size_t)n * 8 + s) * 128 + tid] =
        (unsigned)f2bf(hid[2 * tid]) | ((unsigned)f2bf(hid[2 * tid + 1]) << 16);
}

extern "C" void kernel_launch(void* const* d_in, const int* in_sizes, int n_in,
                              void* d_out, int out_size, void* d_ws, size_t ws_size,
                              hipStream_t stream) {
  (void)in_sizes; (void)n_in; (void)out_size; (void)ws_size;
  const float* inputs = (const float*)d_in[0];
  const float* noise  = (const float*)d_in[1];
  const float* smu    = (const float*)d_in[2];
  const float* slsig  = (const float*)d_in[3];
  const float* Wq     = (const float*)d_in[4];
  const float* Wk     = (const float*)d_in[5];
  const float* Wv     = (const float*)d_in[6];
  const float* W_ih   = (const float*)d_in[7];
  const float* W_hh   = (const float*)d_in[8];
  const float* b_ih   = (const float*)d_in[9];
  const float* b_hh   = (const float*)d_in[10];
  const float* W1     = (const float*)d_in[11];
  const float* b1     = (const float*)d_in[12];
  const float* W2     = (const float*)d_in[13];
  const float* b2     = (const float*)d_in[14];
  const float* lin_g  = (const float*)d_in[15];
  const float* lin_b  = (const float*)d_in[16];
  const float* lsl_g  = (const float*)d_in[17];
  const float* lsl_b  = (const float*)d_in[18];
  const float* lml_g  = (const float*)d_in[19];
  const float* lml_b  = (const float*)d_in[20];
  float* out = (float*)d_out;
  char* ws = (char*)d_ws;
  unsigned* x    = (unsigned*)(ws + 0);            // 134217728
  unsigned* qwb  = (unsigned*)(ws + 134217728);    // 262144
  float* stats   = (float*)(ws + 134479872);       // 32768
  float* axp     = (float*)(ws + 134610944);       // 8388608
  float* WqT     = (float*)(ws + 168165376);       // 262144
  float* WvT     = (float*)(ws + 168427520);       // 262144
  float* WihT    = (float*)(ws + 168689664);       // 786432
  float* WhhT    = (float*)(ws + 169476096);       // 786432
  float* W1T     = (float*)(ws + 170262528);       // 262144
  float* W2T     = (float*)(ws + 170524672);       // 262144

  k_pre<<<dim3(66176), 256, 0, stream>>>(inputs, lin_g, lin_b, x,
                                         Wq, Wv, W_ih, W_hh, W1, W2,
                                         WqT, WvT, WihT, WhhT, W1T, W2T);
  k_qw0<<<dim3(BATCH, 8), 256, 0, stream>>>(smu, slsig, noise, lsl_g, lsl_b,
                                            WqT, Wk, out, qwb);
  for (int it = 0; it < 3; ++it) {
    k_att4p<<<dim3(16, BATCH), 256, 0, stream>>>(x, qwb, stats, axp);
    k_update5<<<dim3(BATCH, 8), 256, 0, stream>>>(
        axp, stats, out, WvT, WihT, WhhT, b_ih, b_hh, W1T, b1, W2T, b2,
        lml_g, lml_b, lsl_g, lsl_b, WqT, Wk, qwb, (it < 2) ? 1 : 0, out);
  }
}